// Round 10
// baseline (497.143 us; speedup 1.0000x reference)
//
#include <hip/hip_runtime.h>
#include <math.h>

// Problem constants (fixed by setup_inputs)
constexpr int K_ = 4, B_ = 8, T_ = 800, C_ = 80, S_ = 128, Z_ = 32;
constexpr int KB_ = K_ * B_;        // 32
constexpr int TC_ = T_ * C_;        // 64000

#define BIGV   1e8f
#define WARP_V 256.0f

// Block-anti-diagonal banded D layout (R7-validated):
//   cell (i, c) 0-based -> row-block t = i>>2, d2 = t + c, slot = t - tmin(d2),
//   stored as float4 at D2[d2*W2*4 + slot*4]. Band: c - 4t in [-124, 127].
constexpr int W2_   = 52;
constexpr int PD2_  = 1000;               // real d2 in [0, 998]
constexpr int SLAB2_ = PD2_ * W2_ * 4;    // 208,000 floats per problem
// Padded, clamp-free addressing (R9-validated). Pads pre-filled with BIGV
// (NOT 0xAA junk: tiny/negative junk would create off-band shortcuts).
constexpr int HEADP_ = 10240;             // floats (min offset -9984)
constexpr int TAILP_ = 16384;             // floats (max overflow +14264)
constexpr int DMTOT_ = HEADP_ + KB_ * SLAB2_ + TAILP_;   // 6,682,624 floats

__device__ __forceinline__ int tmin_of(int d2) {
    int t = (d2 - 123) / 5;               // == max(0, ceil((d2-127)/5)) for d2>=0
    return t > 0 ? t : 0;
}

__device__ __forceinline__ float sigmoidf_(float v) {
    return 1.f / (1.f + __expf(-v));
}

// ---------------------------------------------------------------- fill pads + slab with BIGV
__global__ void fill_big(float4* __restrict__ p, int n4) {
    int i = blockIdx.x * blockDim.x + threadIdx.x;
    if (i < n4) p[i] = make_float4(BIGV, BIGV, BIGV, BIGV);
}

// ---------------------------------------------------------------- banded GEMM -> D2 (norms fused)
// grid (5, 13, 32): tiles with |ti-tj| <= 2 (covers the |i-j| <= 127 DP band).
__global__ __launch_bounds__(256) void gemm_band(const float* __restrict__ mel_iters,
                                                 const float* __restrict__ mel_targets,
                                                 float* __restrict__ Dm) {
    const int kb = blockIdx.z;
    const int b  = kb & 7;
    const int ti = blockIdx.y;
    const int tj = ti + (int)blockIdx.x - 2;
    if ((unsigned)tj > 12u) return;

    const float* __restrict__ Xb = mel_iters + (size_t)kb * TC_;
    const float* __restrict__ Yb = mel_targets + (size_t)b * TC_;

    __shared__ float xa[16][68];   // [k][i] (sigmoid applied)
    __shared__ float ya[16][68];   // [k][j]
    __shared__ float x2s[64], y2s[64];

    const int tid = threadIdx.x;
    const int tx = tid & 15, ty = tid >> 4;
    const int i0 = ti * 64, j0 = tj * 64;
    const int lr = tid >> 4;   // 0..15
    const int lc = tid & 15;   // 0..15  (k within chunk)

    float acc[4][4] = {};
    float nsum = 0.f;          // row-norm partial (tid<64: x2 row tid; tid in [64,128): y2)

    for (int kk = 0; kk < C_; kk += 16) {
        __syncthreads();
        #pragma unroll
        for (int q = 0; q < 4; ++q) {
            int row = lr + q * 16;       // 0..63
            int gi = i0 + row;
            xa[lc][row] = (gi < T_) ? sigmoidf_(Xb[(size_t)gi * C_ + kk + lc]) : 0.f;
            int gj = j0 + row;
            ya[lc][row] = (gj < T_) ? sigmoidf_(Yb[(size_t)gj * C_ + kk + lc]) : 0.f;
        }
        __syncthreads();
        if (tid < 64) {
            #pragma unroll
            for (int k = 0; k < 16; ++k) { float v = xa[k][tid]; nsum += v * v; }
        } else if (tid < 128) {
            #pragma unroll
            for (int k = 0; k < 16; ++k) { float v = ya[k][tid - 64]; nsum += v * v; }
        }
        #pragma unroll
        for (int k = 0; k < 16; ++k) {
            float4 av = *(const float4*)&xa[k][ty * 4];
            float4 bv = *(const float4*)&ya[k][tx * 4];
            acc[0][0] += av.x * bv.x; acc[0][1] += av.x * bv.y; acc[0][2] += av.x * bv.z; acc[0][3] += av.x * bv.w;
            acc[1][0] += av.y * bv.x; acc[1][1] += av.y * bv.y; acc[1][2] += av.y * bv.z; acc[1][3] += av.y * bv.w;
            acc[2][0] += av.z * bv.x; acc[2][1] += av.z * bv.y; acc[2][2] += av.z * bv.z; acc[2][3] += av.z * bv.w;
            acc[3][0] += av.w * bv.x; acc[3][1] += av.w * bv.y; acc[3][2] += av.w * bv.z; acc[3][3] += av.w * bv.w;
        }
    }
    if (tid < 64) x2s[tid] = nsum;
    else if (tid < 128) y2s[tid - 64] = nsum;
    __syncthreads();

    // epilogue: D[i][j] = x2[i] + y2[j] - 2*dot into block-anti-diagonal layout
    const int ib = i0 + ty * 4, jb = j0 + tx * 4;
    if (ib >= T_) return;   // ib 4-aligned, T_=800 -> all-or-nothing
    float xs2[4], ys2[4];
    #pragma unroll
    for (int r = 0; r < 4; ++r) xs2[r] = x2s[ty * 4 + r];
    #pragma unroll
    for (int c = 0; c < 4; ++c) ys2[c] = y2s[tx * 4 + c];

    const int tblk = ib >> 2;
    float* __restrict__ D2b = Dm + HEADP_ + (size_t)kb * SLAB2_;
    #pragma unroll
    for (int c = 0; c < 4; ++c) {
        int j = jb + c;
        if (j >= T_) continue;
        int d2 = tblk + j;
        int sl = tblk - tmin_of(d2);
        if ((unsigned)sl > (unsigned)(W2_ - 1)) continue;   // out of DP band: never read by in-band lanes
        float4 o;
        o.x = xs2[0] + ys2[c] - 2.f * acc[0][c];
        o.y = xs2[1] + ys2[c] - 2.f * acc[1][c];
        o.z = xs2[2] + ys2[c] - 2.f * acc[2][c];
        o.w = xs2[3] + ys2[c] - 2.f * acc[3][c];
        *(float4*)(D2b + (size_t)d2 * (W2_ * 4) + sl * 4) = o;
    }
}

// ---------------------------------------------------------------- banded hard-min DTW, r=4 systolic
// R10: FOUR problems per block (1024 thr = 16 waves, 4 waves/SIMD).
// R9 measured: 2 waves/SIMD hides ~40% of the per-step latency (359 -> 216
// cyc/step-problem per CU); 4/SIMD should saturate the issue port
// (max(4I, I+L)/4 ~ I ~ 115 cyc). Each 256-thread slice runs the
// R8-validated pipeline: thread t owns DP rows 4t+1..4t+4, lane skew 1,
// wave skew G=80, barrier every 8 steps, 3 rotating register load buffers
// with vmcnt(16), clamp-free padded addressing.
constexpr int G3_   = 80;
constexpr int NPH3_ = 132;   // 132*8 = 1056 > last active step 1046; 132 = 3*44

__device__ __forceinline__ void lds_barrier_keep_vmcnt() {
    asm volatile("" ::: "memory");
    // simm16: vmcnt=63 (keep global loads in flight), expcnt=7, lgkmcnt=0
    __builtin_amdgcn_s_waitcnt(0xC07F);
    __builtin_amdgcn_s_barrier();
    asm volatile("" ::: "memory");
}

__device__ __forceinline__ float wave_shr1(float x) {
    // DPP wave_shr1 (0x138): lane l gets lane l-1's value; lane 0 -> 0 (overridden)
    int v = __builtin_amdgcn_update_dpp(0, __float_as_int(x), 0x138, 0xf, 0xf, true);
    return __int_as_float(v);
}

__global__ __launch_bounds__(1024) void dtw_hard_kernel(const float* __restrict__ Dm,
                                                        float* __restrict__ dtwv) {
    __shared__ float ring[4][3 * 64];
    const int kb  = blockIdx.x * 4 + (threadIdx.x >> 8);   // problem id
    const int ptid = threadIdx.x & 255;                    // problem-local tid
    const int l = ptid & 63;
    const int wu = __builtin_amdgcn_readfirstlane(ptid >> 6);   // problem-local wave 0..3
    const int pb = __builtin_amdgcn_readfirstlane(threadIdx.x >> 8);
    const bool is_l63w = (l == 63) && (wu < 3);    // ring writers
    const float* __restrict__ Dd = Dm + HEADP_ + (size_t)kb * SLAB2_;
    float* rng = ring[pb];

    const float dg1 = (ptid == 0) ? 0.f : BIGV;    // R[i-1][0] override at jj==1
    const int goff = G3_ * wu;
    const int wm1 = (wu > 0 ? wu - 1 : 0) * 64;
    const int low_w  = max(1, 256 * wu - 127);
    const int high_w = min(800, 256 * wu + 124);
    const int rslot = wu * 64;
    const int lane4 = (64 * wu + l) * 4;           // slot-0-relative float offset

    if (ptid < 192) rng[ptid] = BIGV;
    __syncthreads();

    // DP state: R[4t+1..4t+4][jj-1] in registers; tprev = R[4t][jj-1]
    float r0s = BIGV, r1s = BIGV, r2s = BIGV, r3s = BIGV;
    float tprev = BIGV;
    float res = 0.f;
    int jj = 1 - goff - l;                         // this lane's column at step 0

    // Batched coalesced clamp-free D2 loads for steps [s_base, s_base+8)
    auto batch_load = [&](float4 (&buf)[8], int s_base) {
        #pragma unroll
        for (int k = 0; k < 8; ++k) {
            int d2 = s_base + k - 16 * wu;                       // wave-uniform
            int tm = (d2 - 123) / 5; tm = tm < 0 ? 0 : tm;       // SALU
            int ro = __builtin_amdgcn_readfirstlane(d2 * (W2_ * 4) - tm * 4);
            buf[k] = *(const float4*)(Dd + ro + lane4);
        }
    };

    float rvA[8], rvB[8], rvC[8];
    auto prefetch_ring = [&](float (&rv)[8], int pp) {   // values consumed during phase pp
        #pragma unroll
        for (int k = 0; k < 8; ++k) {
            int j0 = 8 * pp + k + 1 - goff;              // lane-0 column at step 8*pp+k
            float rr = rng[wm1 + (j0 & 63)];
            rv[k] = (wu > 0 && j0 >= low_w && j0 <= high_w) ? rr : BIGV;
        }
    };

    // result lane: ptid==199 (rows 797..800, wu=3, l=7) hits jj==800 at
    // step s = 800-1+goff+l = 1046 = 8*130+6 -> capture at sp==1040, k==6.
    const bool is_res = (ptid == 199);

    auto run8 = [&](const float4 (&buf)[8], const float (&rv)[8], int sp) {
        #pragma unroll
        for (int k = 0; k < 8; ++k) {
            float4 d = buf[k];
            float tin  = wave_shr1(r3s);                 // lane l-1's bottom value (prev step)
            float tcur = (l == 0) ? rv[k] : tin;         // R[i0-1][jj]
            float dg   = (jj == 1) ? dg1 : tprev;        // R[i0-1][jj-1]
            float dxW = d.x + WARP_V;
            float n0 = fminf(fminf(dg + d.x, tcur + dxW), r0s + dxW);   // v_min3
            float dyW = d.y + WARP_V;
            float n1 = fminf(fminf(r0s + d.y, n0 + dyW), r1s + dyW);
            float dzW = d.z + WARP_V;
            float n2 = fminf(fminf(r1s + d.z, n1 + dzW), r2s + dzW);
            float dwW = d.w + WARP_V;
            float n3 = fminf(fminf(r2s + d.w, n2 + dwW), r3s + dwW);
            if (is_l63w) rng[rslot + (jj & 63)] = n3;
            if (k == 6 && sp == 1040 && is_res) res = n3;   // R[800][800]
            r0s = n0; r1s = n1; r2s = n2; r3s = n3;
            tprev = tcur;
            ++jj;
        }
    };

    // preload phases 0 and 1; phase 0's ring values are all masked-BIG anyway
    float4 bufA[8], bufB[8], bufC[8];
    batch_load(bufA, 0);
    batch_load(bufB, 8);
    prefetch_ring(rvA, 0);

    int sp = 0;
    for (int p = 0; p < NPH3_; p += 3) {
        batch_load(bufC, sp + 16);
        asm volatile("s_waitcnt vmcnt(16)" ::: "memory");   // bufA complete; B,C in flight
        prefetch_ring(rvB, p + 1);
        run8(bufA, rvA, sp);
        lds_barrier_keep_vmcnt();
        sp += 8;

        batch_load(bufA, sp + 16);
        asm volatile("s_waitcnt vmcnt(16)" ::: "memory");   // bufB complete
        prefetch_ring(rvC, p + 2);
        run8(bufB, rvB, sp);
        lds_barrier_keep_vmcnt();
        sp += 8;

        batch_load(bufB, sp + 16);
        asm volatile("s_waitcnt vmcnt(16)" ::: "memory");   // bufC complete
        prefetch_ring(rvA, p + 3);
        run8(bufC, rvC, sp);
        lds_barrier_keep_vmcnt();
        sp += 8;
    }

    if (is_res) dtwv[kb] = res;
}

// ---------------------------------------------------------------- finalize (scalars)
__global__ void finalize_kernel(const float* __restrict__ dtwv, const int* __restrict__ mel_lens,
                                const int* __restrict__ src_lens, const float* __restrict__ durations,
                                const float* __restrict__ mus, const float* __restrict__ log_vars,
                                const int* __restrict__ step, float* __restrict__ out) {
    const int lane = threadIdx.x;  // 64 threads, one wave

    float v = (lane < KB_) ? dtwv[lane] : 0.f;
    for (int o = 32; o; o >>= 1) v += __shfl_down(v, o);

    float w = (lane < B_) ? 1.f / (K_ * (float)mel_lens[lane]) : 0.f;
    for (int o = 32; o; o >>= 1) w += __shfl_down(w, o);

    float du = 0.f;
    if (lane < B_) {
        float s = 0.f;
        for (int j = 0; j < S_; ++j) s += durations[lane * S_ + j];
        du = fabsf(s - (float)mel_lens[lane]) / (float)src_lens[lane];
    }
    for (int o = 32; o; o >>= 1) du += __shfl_down(du, o);

    float kl = 0.f;
    for (int j = lane; j < B_ * Z_; j += 64) {
        float muv = mus[j], lv = log_vars[j];
        kl += 1.f + lv - muv * muv - expf(lv);
    }
    for (int o = 32; o; o >>= 1) kl += __shfl_down(kl, o);

    if (lane == 0) {
        float mel_iter_loss = v / (float)B_;
        float mel_loss = mel_iter_loss * (w / (float)B_);
        float dur_loss = 2.0f * du / (float)B_;
        float kl_loss = -0.5f * kl;
        int st = step[0];
        float beta = (st < 2000) ? 0.f : ((st >= 8000) ? 1.f : (float)(st - 2000) / 6000.f);
        out[0] = mel_loss + dur_loss + beta * kl_loss;
        out[1] = mel_loss;
        out[2] = dur_loss;
        out[3] = kl_loss;
        out[4] = beta;
    }
}

// ---------------------------------------------------------------- launch
extern "C" void kernel_launch(void* const* d_in, const int* in_sizes, int n_in,
                              void* d_out, int out_size, void* d_ws, size_t ws_size,
                              hipStream_t stream) {
    const float* mel_iters   = (const float*)d_in[0];
    const float* mel_targets = (const float*)d_in[1];
    const int*   mel_lens    = (const int*)d_in[2];
    const int*   src_lens    = (const int*)d_in[3];
    const float* durations   = (const float*)d_in[4];
    const float* mus         = (const float*)d_in[5];
    const float* log_vars    = (const float*)d_in[6];
    const int*   step        = (const int*)d_in[7];
    float* out = (float*)d_out;

    float* ws   = (float*)d_ws;
    float* Dm   = ws;                              // DMTOT_ = 6,682,624 floats (26.7 MB, padded)
    float* dtwv = Dm + (size_t)DMTOT_;             //        32

    const int n4 = DMTOT_ / 4;
    fill_big<<<(n4 + 255) / 256, 256, 0, stream>>>((float4*)Dm, n4);

    gemm_band<<<dim3(5, 13, KB_), 256, 0, stream>>>(mel_iters, mel_targets, Dm);

    dtw_hard_kernel<<<KB_ / 4, 1024, 0, stream>>>(Dm, dtwv);

    finalize_kernel<<<1, 64, 0, stream>>>(dtwv, mel_lens, src_lens, durations, mus, log_vars, step, out);
}

// Round 11
// 267.417 us; speedup vs baseline: 1.8591x; 1.8591x over previous
//
#include <hip/hip_runtime.h>
#include <math.h>

// Problem constants (fixed by setup_inputs)
constexpr int K_ = 4, B_ = 8, T_ = 800, C_ = 80, S_ = 128, Z_ = 32;
constexpr int KB_ = K_ * B_;        // 32
constexpr int TC_ = T_ * C_;        // 64000

#define BIGV   1e8f
#define WARP_V 256.0f

// R11 stream layout: one wave per problem, lane l owns 0-based rows
// [16l, 16l+15] (l = 0..49), sweeping col c = u - l at step u.
// Q[u][l][q] (float4) = D[16l+4q .. 16l+4q+3][c = u - l].
// Per step the wave reads Q[u][0..49][0..3] with per-lane 64B contiguity.
// Lane col window: c in [16l-127, 16l+142] (clamped [0,799]) -> u window
// [c_lo+l, c_hi+l]; out-of-window steps reuse the clamped edge slot (real D,
// safe: any path at deviation >142 pays >= 142*256 = 36k >> optimal ~18k).
constexpr int NU_    = 852;               // u slots (max real u = 848)
constexpr int SLAB3_ = NU_ * 800;         // 681,600 floats per problem (50 lanes x 16)

__device__ __forceinline__ float sigmoidf_(float v) {
    return 1.f / (1.f + __expf(-v));
}

// ---------------------------------------------------------------- banded GEMM -> Q-stream (norms fused)
// grid (7, 13, 32): tiles with |ti-tj| <= 3 (covers all |i-c| <= 142 lane-window cells).
__global__ __launch_bounds__(256) void gemm_band(const float* __restrict__ mel_iters,
                                                 const float* __restrict__ mel_targets,
                                                 float* __restrict__ Dm) {
    const int kb = blockIdx.z;
    const int b  = kb & 7;
    const int ti = blockIdx.y;
    const int tj = ti + (int)blockIdx.x - 3;
    if ((unsigned)tj > 12u) return;

    const float* __restrict__ Xb = mel_iters + (size_t)kb * TC_;
    const float* __restrict__ Yb = mel_targets + (size_t)b * TC_;

    __shared__ float xa[16][68];   // [k][i] (sigmoid applied)
    __shared__ float ya[16][68];   // [k][j]
    __shared__ float x2s[64], y2s[64];

    const int tid = threadIdx.x;
    const int tx = tid & 15, ty = tid >> 4;
    const int i0 = ti * 64, j0 = tj * 64;
    const int lr = tid >> 4;   // 0..15
    const int lc = tid & 15;   // 0..15  (k within chunk)

    float acc[4][4] = {};
    float nsum = 0.f;          // row-norm partial (tid<64: x2 row tid; tid in [64,128): y2)

    for (int kk = 0; kk < C_; kk += 16) {
        __syncthreads();
        #pragma unroll
        for (int q = 0; q < 4; ++q) {
            int row = lr + q * 16;       // 0..63
            int gi = i0 + row;
            xa[lc][row] = (gi < T_) ? sigmoidf_(Xb[(size_t)gi * C_ + kk + lc]) : 0.f;
            int gj = j0 + row;
            ya[lc][row] = (gj < T_) ? sigmoidf_(Yb[(size_t)gj * C_ + kk + lc]) : 0.f;
        }
        __syncthreads();
        if (tid < 64) {
            #pragma unroll
            for (int k = 0; k < 16; ++k) { float v = xa[k][tid]; nsum += v * v; }
        } else if (tid < 128) {
            #pragma unroll
            for (int k = 0; k < 16; ++k) { float v = ya[k][tid - 64]; nsum += v * v; }
        }
        #pragma unroll
        for (int k = 0; k < 16; ++k) {
            float4 av = *(const float4*)&xa[k][ty * 4];
            float4 bv = *(const float4*)&ya[k][tx * 4];
            acc[0][0] += av.x * bv.x; acc[0][1] += av.x * bv.y; acc[0][2] += av.x * bv.z; acc[0][3] += av.x * bv.w;
            acc[1][0] += av.y * bv.x; acc[1][1] += av.y * bv.y; acc[1][2] += av.y * bv.z; acc[1][3] += av.y * bv.w;
            acc[2][0] += av.z * bv.x; acc[2][1] += av.z * bv.y; acc[2][2] += av.z * bv.z; acc[2][3] += av.z * bv.w;
            acc[3][0] += av.w * bv.x; acc[3][1] += av.w * bv.y; acc[3][2] += av.w * bv.z; acc[3][3] += av.w * bv.w;
        }
    }
    if (tid < 64) x2s[tid] = nsum;
    else if (tid < 128) y2s[tid - 64] = nsum;
    __syncthreads();

    // epilogue: D[i][j] = x2[i] + y2[j] - 2*dot into the Q-stream
    const int ib = i0 + ty * 4, jb = j0 + tx * 4;
    if (ib >= T_) return;   // ib 4-aligned, T_=800 -> all-or-nothing
    float xs2[4], ys2[4];
    #pragma unroll
    for (int r = 0; r < 4; ++r) xs2[r] = x2s[ty * 4 + r];
    #pragma unroll
    for (int c = 0; c < 4; ++c) ys2[c] = y2s[tx * 4 + c];

    const int l = ib >> 4;                 // DP lane owning these rows
    const int q = (ib >> 2) & 3;           // quad within the lane
    const int w_lo = max(0, 16 * l - 127); // lane col window
    const int w_hi = min(799, 16 * l + 142);

    float* __restrict__ Db = Dm + (size_t)kb * SLAB3_;
    #pragma unroll
    for (int c = 0; c < 4; ++c) {
        int j = jb + c;
        if (j < w_lo || j > w_hi) continue;   // slot never read by the DP
        float4 o;
        o.x = xs2[0] + ys2[c] - 2.f * acc[0][c];
        o.y = xs2[1] + ys2[c] - 2.f * acc[1][c];
        o.z = xs2[2] + ys2[c] - 2.f * acc[2][c];
        o.w = xs2[3] + ys2[c] - 2.f * acc[3][c];
        *(float4*)(Db + (size_t)(j + l) * 800 + l * 16 + q * 4) = o;
    }
}

// ---------------------------------------------------------------- single-wave hard-min DTW, r=16
// One 64-thread block (ONE wave) per problem: zero barriers, zero LDS, zero
// per-step masks. Lane l owns rows 16l..16l+15 (0-based), sweeps col c = u - l.
// Row handoff: DPP wave_shr1 of S[15] (previous step). Loads: 3 rotating
// register batches of 4 steps (16 dwordx4 each), clamped via med3 to the lane
// window (frozen-edge reads are cached + provably harmless).
__device__ __forceinline__ float wave_shr1(float x) {
    int v = __builtin_amdgcn_update_dpp(0, __float_as_int(x), 0x138, 0xf, 0xf, true);
    return __int_as_float(v);
}

__global__ __launch_bounds__(64, 1) void dtw_wave_kernel(const float* __restrict__ Dm,
                                                         float* __restrict__ dtwv) {
    const int kb = blockIdx.x;
    const int l  = threadIdx.x;                 // 0..63
    const int lc = l < 49 ? l : 49;             // lanes 50-63 mirror lane 49 (results unused)
    const bool is_l0 = (l == 0);
    const float* __restrict__ Dd = Dm + (size_t)kb * SLAB3_;

    const int lo_u = max(0, 16 * lc - 127) + lc;     // first in-window u
    const int hi_u = min(799, 16 * lc + 142) + lc;   // last in-window u
    const int lofs = lc * 16;                        // lane float offset within a u-slot

    // DP state: S[k] = R[16l+k][c-1]; tprev = R[16l-1][c-1] (via lane l-1)
    float S[16];
    #pragma unroll
    for (int k = 0; k < 16; ++k) S[k] = BIGV;
    float tprev = (l == 0) ? 0.f : BIGV;   // lane0 c=0 diag = R[-1][-1] = 0

    auto load_batch = [&](float4 (&buf)[4][4], int ub) {
        #pragma unroll
        for (int j = 0; j < 4; ++j) {
            int u_c = ub + j;
            u_c = u_c < lo_u ? lo_u : (u_c > hi_u ? hi_u : u_c);   // v_med3
            const float* p = Dd + u_c * 800 + lofs;
            #pragma unroll
            for (int q = 0; q < 4; ++q) buf[j][q] = *(const float4*)(p + q * 4);
        }
    };

    auto step = [&](const float4 (&dq)[4]) {
        float tin  = wave_shr1(S[15]);          // lane l-1's bottom value, prev step
        float tcur = is_l0 ? BIGV : tin;        // R[16l-1][c]
        float dgv = tprev;                      // R[row-1][c-1]
        float up  = tcur;                       // R[row-1][c]
        #pragma unroll
        for (int q = 0; q < 4; ++q) {
            float4 d = dq[q];
            float oS, dW, n;
            oS = S[4*q+0]; dW = d.x + WARP_V;
            n = fminf(fminf(dgv + d.x, up + dW), oS + dW);
            dgv = oS; up = n; S[4*q+0] = n;
            oS = S[4*q+1]; dW = d.y + WARP_V;
            n = fminf(fminf(dgv + d.y, up + dW), oS + dW);
            dgv = oS; up = n; S[4*q+1] = n;
            oS = S[4*q+2]; dW = d.z + WARP_V;
            n = fminf(fminf(dgv + d.z, up + dW), oS + dW);
            dgv = oS; up = n; S[4*q+2] = n;
            oS = S[4*q+3]; dW = d.w + WARP_V;
            n = fminf(fminf(dgv + d.w, up + dW), oS + dW);
            dgv = oS; up = n; S[4*q+3] = n;
        }
        tprev = tcur;
    };

    auto run4 = [&](const float4 (&buf)[4][4]) {
        #pragma unroll
        for (int j = 0; j < 4; ++j) step(buf[j]);
    };

    float4 bufA[4][4], bufB[4][4], bufC[4][4];
    load_batch(bufA, 0);
    load_batch(bufB, 4);

    int u = 0;
    for (int g = 0; g < 70; ++g) {     // 210 batches = steps u = 0..839
        load_batch(bufC, u + 8);
        asm volatile("s_waitcnt vmcnt(32)" ::: "memory");
        run4(bufA);
        u += 4;
        load_batch(bufA, u + 8);
        asm volatile("s_waitcnt vmcnt(32)" ::: "memory");
        run4(bufB);
        u += 4;
        load_batch(bufB, u + 8);
        asm volatile("s_waitcnt vmcnt(32)" ::: "memory");
        run4(bufC);
        u += 4;
    }
    // u = 840: remaining batches b210 (bufA), b211 (bufB), then step u=848
    load_batch(bufC, 848);                              // b212 (only step 0 used)
    asm volatile("s_waitcnt vmcnt(32)" ::: "memory");
    run4(bufA);                                         // u = 840..843
    asm volatile("s_waitcnt vmcnt(0)" ::: "memory");
    run4(bufB);                                         // u = 844..847
    step(bufC[0]);                                      // u = 848: lane 49 col 799

    if (l == 49) dtwv[kb] = S[15];                      // R[800][800]
}

// ---------------------------------------------------------------- finalize (scalars)
__global__ void finalize_kernel(const float* __restrict__ dtwv, const int* __restrict__ mel_lens,
                                const int* __restrict__ src_lens, const float* __restrict__ durations,
                                const float* __restrict__ mus, const float* __restrict__ log_vars,
                                const int* __restrict__ step, float* __restrict__ out) {
    const int lane = threadIdx.x;  // 64 threads, one wave

    float v = (lane < KB_) ? dtwv[lane] : 0.f;
    for (int o = 32; o; o >>= 1) v += __shfl_down(v, o);

    float w = (lane < B_) ? 1.f / (K_ * (float)mel_lens[lane]) : 0.f;
    for (int o = 32; o; o >>= 1) w += __shfl_down(w, o);

    float du = 0.f;
    if (lane < B_) {
        float s = 0.f;
        for (int j = 0; j < S_; ++j) s += durations[lane * S_ + j];
        du = fabsf(s - (float)mel_lens[lane]) / (float)src_lens[lane];
    }
    for (int o = 32; o; o >>= 1) du += __shfl_down(du, o);

    float kl = 0.f;
    for (int j = lane; j < B_ * Z_; j += 64) {
        float muv = mus[j], lv = log_vars[j];
        kl += 1.f + lv - muv * muv - expf(lv);
    }
    for (int o = 32; o; o >>= 1) kl += __shfl_down(kl, o);

    if (lane == 0) {
        float mel_iter_loss = v / (float)B_;
        float mel_loss = mel_iter_loss * (w / (float)B_);
        float dur_loss = 2.0f * du / (float)B_;
        float kl_loss = -0.5f * kl;
        int st = step[0];
        float beta = (st < 2000) ? 0.f : ((st >= 8000) ? 1.f : (float)(st - 2000) / 6000.f);
        out[0] = mel_loss + dur_loss + beta * kl_loss;
        out[1] = mel_loss;
        out[2] = dur_loss;
        out[3] = kl_loss;
        out[4] = beta;
    }
}

// ---------------------------------------------------------------- launch
extern "C" void kernel_launch(void* const* d_in, const int* in_sizes, int n_in,
                              void* d_out, int out_size, void* d_ws, size_t ws_size,
                              hipStream_t stream) {
    const float* mel_iters   = (const float*)d_in[0];
    const float* mel_targets = (const float*)d_in[1];
    const int*   mel_lens    = (const int*)d_in[2];
    const int*   src_lens    = (const int*)d_in[3];
    const float* durations   = (const float*)d_in[4];
    const float* mus         = (const float*)d_in[5];
    const float* log_vars    = (const float*)d_in[6];
    const int*   step        = (const int*)d_in[7];
    float* out = (float*)d_out;

    float* ws   = (float*)d_ws;
    float* Dm   = ws;                              // 32 * 681,600 floats = 87.2 MB
    float* dtwv = Dm + (size_t)KB_ * SLAB3_;       //        32

    gemm_band<<<dim3(7, 13, KB_), 256, 0, stream>>>(mel_iters, mel_targets, Dm);

    dtw_wave_kernel<<<KB_, 64, 0, stream>>>(Dm, dtwv);

    finalize_kernel<<<1, 64, 0, stream>>>(dtwv, mel_lens, src_lens, durations, mus, log_vars, step, out);
}

// Round 12
// 265.508 us; speedup vs baseline: 1.8724x; 1.0072x over previous
//
#include <hip/hip_runtime.h>
#include <math.h>

// Problem constants (fixed by setup_inputs)
constexpr int K_ = 4, B_ = 8, T_ = 800, C_ = 80, S_ = 128, Z_ = 32;
constexpr int KB_ = K_ * B_;        // 32
constexpr int TC_ = T_ * C_;        // 64000

#define BIGV   1e8f
#define WARP_V 256.0f

// R12 sheared-stream layout (g=8): Q[u][i] = D[i][u - (i>>3)].
// Lane l owns rows 16l..16l+15 = groups m=0 (cols j0 = u-2l) and m=1 (j1 = j0-1).
// Per step the wave reads Q[u][0..799]: lane reads 64B contiguous, wave 3.2KB.
constexpr int NU_   = 900;            // u = j + (i>>3) <= 799 + 99 = 898
constexpr int SLAB_ = NU_ * 800;      // 720,000 floats per problem (92.16 MB total)

__device__ __forceinline__ float sigmoidf_(float v) {
    return 1.f / (1.f + __expf(-v));
}

// ---------------------------------------------------------------- fill j = -1 ghost cells with BIG
// Lanes l<=11 read Q[2l][16l+8..15] = D[i][-1] once (their first step): must be BIG.
__global__ void fill_edge(float* __restrict__ Dm) {
    int kb = blockIdx.x;
    int t = threadIdx.x;
    if (t < 184) {
        int i = 8 + t;     // i in [8, 191]
        Dm[(size_t)kb * SLAB_ + (size_t)((i >> 3) - 1) * 800 + i] = BIGV;
    }
}

// ---------------------------------------------------------------- banded GEMM -> sheared Q (norms fused)
// grid (5, 13, 32): tiles |ti-tj| <= 2 (written band deviation >= 128 > DP corridor 124).
// Epilogue: LDS shear-transpose -> coalesced 256B u-row stores (edge rows predicated).
__global__ __launch_bounds__(256) void gemm_band(const float* __restrict__ mel_iters,
                                                 const float* __restrict__ mel_targets,
                                                 float* __restrict__ Dm) {
    const int kb = blockIdx.z;
    const int b  = kb & 7;
    const int ti = blockIdx.y;
    const int tj = ti + (int)blockIdx.x - 2;
    if ((unsigned)tj > 12u) return;

    const float* __restrict__ Xb = mel_iters + (size_t)kb * TC_;
    const float* __restrict__ Yb = mel_targets + (size_t)b * TC_;

    __shared__ float smem[4615];            // phase1: xa[16][68] | ya[16][68] | x2s[64] | y2s[64]
    float (*xa)[68] = (float(*)[68])smem;   // phase2: Zt[71][65]
    float (*ya)[68] = (float(*)[68])(smem + 1088);
    float* x2s = smem + 2176;
    float* y2s = smem + 2240;

    const int tid = threadIdx.x;
    const int tx = tid & 15, ty = tid >> 4;
    const int i0 = ti * 64, j0 = tj * 64;
    const int lr = tid >> 4;   // 0..15
    const int lc = tid & 15;   // 0..15  (k within chunk)

    float acc[4][4] = {};
    float nsum = 0.f;          // row-norm partial (tid<64: x2 row tid; tid in [64,128): y2)

    for (int kk = 0; kk < C_; kk += 16) {
        __syncthreads();
        #pragma unroll
        for (int q = 0; q < 4; ++q) {
            int row = lr + q * 16;       // 0..63
            int gi = i0 + row;
            xa[lc][row] = (gi < T_) ? sigmoidf_(Xb[(size_t)gi * C_ + kk + lc]) : 0.f;
            int gj = j0 + row;
            ya[lc][row] = (gj < T_) ? sigmoidf_(Yb[(size_t)gj * C_ + kk + lc]) : 0.f;
        }
        __syncthreads();
        if (tid < 64) {
            #pragma unroll
            for (int k = 0; k < 16; ++k) { float v = xa[k][tid]; nsum += v * v; }
        } else if (tid < 128) {
            #pragma unroll
            for (int k = 0; k < 16; ++k) { float v = ya[k][tid - 64]; nsum += v * v; }
        }
        #pragma unroll
        for (int k = 0; k < 16; ++k) {
            float4 av = *(const float4*)&xa[k][ty * 4];
            float4 bv = *(const float4*)&ya[k][tx * 4];
            acc[0][0] += av.x * bv.x; acc[0][1] += av.x * bv.y; acc[0][2] += av.x * bv.z; acc[0][3] += av.x * bv.w;
            acc[1][0] += av.y * bv.x; acc[1][1] += av.y * bv.y; acc[1][2] += av.y * bv.z; acc[1][3] += av.y * bv.w;
            acc[2][0] += av.z * bv.x; acc[2][1] += av.z * bv.y; acc[2][2] += av.z * bv.z; acc[2][3] += av.z * bv.w;
            acc[3][0] += av.w * bv.x; acc[3][1] += av.w * bv.y; acc[3][2] += av.w * bv.z; acc[3][3] += av.w * bv.w;
        }
    }
    if (tid < 64) x2s[tid] = nsum;
    else if (tid < 128) y2s[tid - 64] = nsum;
    __syncthreads();

    // read norms into regs BEFORE LDS reuse
    float xs2[4], ys2[4];
    #pragma unroll
    for (int r = 0; r < 4; ++r) xs2[r] = x2s[ty * 4 + r];
    #pragma unroll
    for (int c = 0; c < 4; ++c) ys2[c] = y2s[tx * 4 + c];
    __syncthreads();

    // stage into sheared LDS tile: Zt[u_rel][iLoc], u_rel = 4tx + c + (ty>>1)
    float* Zt = smem;                     // [71][65]
    const int sb = ty >> 1;
    #pragma unroll
    for (int r = 0; r < 4; ++r)
        #pragma unroll
        for (int c = 0; c < 4; ++c)
            Zt[(4 * tx + c + sb) * 65 + (4 * ty + r)] = xs2[r] + ys2[c] - 2.f * acc[r][c];
    __syncthreads();

    // coalesced u-row stores: u_global = j0 + 8ti + w, 64 contiguous floats at i0
    const int w0 = tid >> 6;              // wave id 0..3
    const int lane = tid & 63;
    const int iGlob = i0 + lane;
    const int sbl = lane >> 3;            // s(i) - 8ti
    const bool iok = iGlob < T_;
    const size_t ub = (size_t)(j0 + 8 * ti) * 800 + iGlob;
    #pragma unroll
    for (int it = 0; it < 18; ++it) {
        int w = w0 + it * 4;
        if (w > 70) break;
        int jrel = w - sbl;
        if (iok && (unsigned)jrel < 64u && (j0 + jrel) < T_)
            Dm[(size_t)kb * SLAB_ + ub + (size_t)w * 800] = Zt[w * 65 + lane];
    }
}

// ---------------------------------------------------------------- single-wave hard-min DTW, r=16, g=8 shear
// One wave per problem: zero barriers/LDS. Lane l rows 16l..16l+15 in two
// independent 8-chains per step (group-1 inputs = S7 history regs) ->
// chain/step 96 cyc vs issue ~190. Cross-lane: DPP with 2-step history.
__device__ __forceinline__ float wave_shr1(float x) {
    int v = __builtin_amdgcn_update_dpp(0, __float_as_int(x), 0x138, 0xf, 0xf, true);
    return __int_as_float(v);
}

__global__ __launch_bounds__(64, 1) void dtw_wave_kernel(const float* __restrict__ Dm,
                                                         float* __restrict__ dtwv) {
    const int kb = blockIdx.x;
    const int l  = threadIdx.x;
    const int lc = l < 49 ? l : 49;             // lanes 50-63 mirror lane 49
    const bool is_l0 = (l == 0);
    const float* __restrict__ Dd = Dm + (size_t)kb * SLAB_;

    const int ti_l = lc >> 2;
    const int Jlo = ti_l >= 2 ? 64 * (ti_l - 2) : 0;
    const int Jhi = min(799, 64 * ti_l + 191);
    const int lo_u = (Jlo == 0) ? (2 * lc) : (Jlo + 2 * lc + 1);
    const int hi_u = Jhi + 2 * lc + 1;
    const int lofs = lc << 4;

    // DP state
    float s0 = BIGV, s1 = BIGV, s2 = BIGV, s3 = BIGV, s4 = BIGV, s5 = BIGV, s6 = BIGV, s7 = BIGV;
    float s8 = BIGV, s9 = BIGV, s10 = BIGV, s11 = BIGV, s12 = BIGV, s13 = BIGV, s14 = BIGV, s15 = BIGV;
    float s7p = BIGV;                           // S7 two steps ago
    float tinA = BIGV;                          // lane l-1 S15, one step ago
    float tinB = is_l0 ? 0.f : BIGV;            // two steps ago (lane0: diag of (0,0))

    auto load_batch = [&](float4 (&buf)[4][4], int ub) {
        #pragma unroll
        for (int j = 0; j < 4; ++j) {
            int uc = ub + j;
            uc = uc < lo_u ? lo_u : (uc > hi_u ? hi_u : uc);
            const float* p = Dd + (size_t)uc * 800 + lofs;
            buf[j][0] = *(const float4*)(p);
            buf[j][1] = *(const float4*)(p + 4);
            buf[j][2] = *(const float4*)(p + 8);
            buf[j][3] = *(const float4*)(p + 12);
        }
    };

    auto step = [&](const float4 (&dq)[4]) {
        float up8v = s7;                        // S7 after step u-1 (pre-update)
        float dg8v = s7p;                       // S7 after step u-2
        float dgv0 = tinB, upv0 = tinA;
        float dgv1 = dg8v, upv1 = up8v;
        #define CELL2(SA, DA, SB, DB)                                             \
        {   float oA = SA; float wA = (DA) + WARP_V;                              \
            float nA = fminf(fminf(dgv0 + (DA), upv0 + wA), oA + wA);             \
            dgv0 = oA; upv0 = nA; SA = nA;                                        \
            float oB = SB; float wB = (DB) + WARP_V;                              \
            float nB = fminf(fminf(dgv1 + (DB), upv1 + wB), oB + wB);             \
            dgv1 = oB; upv1 = nB; SB = nB;                                        \
        }
        CELL2(s0, dq[0].x, s8,  dq[2].x);
        CELL2(s1, dq[0].y, s9,  dq[2].y);
        CELL2(s2, dq[0].z, s10, dq[2].z);
        CELL2(s3, dq[0].w, s11, dq[2].w);
        CELL2(s4, dq[1].x, s12, dq[3].x);
        CELL2(s5, dq[1].y, s13, dq[3].y);
        CELL2(s6, dq[1].z, s14, dq[3].z);
        CELL2(s7, dq[1].w, s15, dq[3].w);
        #undef CELL2
        s7p = up8v;
        float hand = wave_shr1(s15);
        tinB = tinA;
        tinA = is_l0 ? BIGV : hand;
    };

    auto run4 = [&](const float4 (&buf)[4][4]) {
        #pragma unroll
        for (int j = 0; j < 4; ++j) step(buf[j]);
    };

    float4 bufA[4][4], bufB[4][4], bufC[4][4];
    load_batch(bufA, 0);
    load_batch(bufB, 4);

    int u = 0;
    for (int g = 0; g < 74; ++g) {       // batches 0..221, steps 0..887
        load_batch(bufC, u + 8);
        asm volatile("s_waitcnt vmcnt(32)" ::: "memory");
        run4(bufA);
        u += 4;
        load_batch(bufA, u + 8);
        asm volatile("s_waitcnt vmcnt(32)" ::: "memory");
        run4(bufB);
        u += 4;
        load_batch(bufB, u + 8);
        asm volatile("s_waitcnt vmcnt(32)" ::: "memory");
        run4(bufC);
        u += 4;
    }
    // u = 888: A = 888..891, B = 892..895
    load_batch(bufC, 896);
    asm volatile("s_waitcnt vmcnt(32)" ::: "memory");
    run4(bufA);                                         // 888..891
    asm volatile("s_waitcnt vmcnt(16)" ::: "memory");
    run4(bufB);                                         // 892..895
    asm volatile("s_waitcnt vmcnt(0)" ::: "memory");
    step(bufC[0]);                                      // 896
    step(bufC[1]);                                      // 897
    step(bufC[2]);                                      // 898: lane 49 s15 = R[800][800]

    if (l == 49) dtwv[kb] = s15;
}

// ---------------------------------------------------------------- finalize (scalars)
__global__ void finalize_kernel(const float* __restrict__ dtwv, const int* __restrict__ mel_lens,
                                const int* __restrict__ src_lens, const float* __restrict__ durations,
                                const float* __restrict__ mus, const float* __restrict__ log_vars,
                                const int* __restrict__ step, float* __restrict__ out) {
    const int lane = threadIdx.x;  // 64 threads, one wave

    float v = (lane < KB_) ? dtwv[lane] : 0.f;
    for (int o = 32; o; o >>= 1) v += __shfl_down(v, o);

    float w = (lane < B_) ? 1.f / (K_ * (float)mel_lens[lane]) : 0.f;
    for (int o = 32; o; o >>= 1) w += __shfl_down(w, o);

    float du = 0.f;
    if (lane < B_) {
        float s = 0.f;
        for (int j = 0; j < S_; ++j) s += durations[lane * S_ + j];
        du = fabsf(s - (float)mel_lens[lane]) / (float)src_lens[lane];
    }
    for (int o = 32; o; o >>= 1) du += __shfl_down(du, o);

    float kl = 0.f;
    for (int j = lane; j < B_ * Z_; j += 64) {
        float muv = mus[j], lv = log_vars[j];
        kl += 1.f + lv - muv * muv - expf(lv);
    }
    for (int o = 32; o; o >>= 1) kl += __shfl_down(kl, o);

    if (lane == 0) {
        float mel_iter_loss = v / (float)B_;
        float mel_loss = mel_iter_loss * (w / (float)B_);
        float dur_loss = 2.0f * du / (float)B_;
        float kl_loss = -0.5f * kl;
        int st = step[0];
        float beta = (st < 2000) ? 0.f : ((st >= 8000) ? 1.f : (float)(st - 2000) / 6000.f);
        out[0] = mel_loss + dur_loss + beta * kl_loss;
        out[1] = mel_loss;
        out[2] = dur_loss;
        out[3] = kl_loss;
        out[4] = beta;
    }
}

// ---------------------------------------------------------------- launch
extern "C" void kernel_launch(void* const* d_in, const int* in_sizes, int n_in,
                              void* d_out, int out_size, void* d_ws, size_t ws_size,
                              hipStream_t stream) {
    const float* mel_iters   = (const float*)d_in[0];
    const float* mel_targets = (const float*)d_in[1];
    const int*   mel_lens    = (const int*)d_in[2];
    const int*   src_lens    = (const int*)d_in[3];
    const float* durations   = (const float*)d_in[4];
    const float* mus         = (const float*)d_in[5];
    const float* log_vars    = (const float*)d_in[6];
    const int*   step        = (const int*)d_in[7];
    float* out = (float*)d_out;

    float* ws   = (float*)d_ws;
    float* Dm   = ws;                              // 32 * 720,000 floats = 92.16 MB
    float* dtwv = Dm + (size_t)KB_ * SLAB_;        //        32

    fill_edge<<<KB_, 192, 0, stream>>>(Dm);

    gemm_band<<<dim3(5, 13, KB_), 256, 0, stream>>>(mel_iters, mel_targets, Dm);

    dtw_wave_kernel<<<KB_, 64, 0, stream>>>(Dm, dtwv);

    finalize_kernel<<<1, 64, 0, stream>>>(dtwv, mel_lens, src_lens, durations, mus, log_vars, step, out);
}